// Round 1
// baseline (6160.402 us; speedup 1.0000x reference)
//
#include <hip/hip_runtime.h>
#include <hip/hip_bf16.h>
#include <stdint.h>

// DIORA inside pass. B=128, T=32, D=400, ncells=528.
// Strategy: per-cell transform caching. For each chart cell, once its h/c are
// computed, immediately compute 5 linear transforms (h@u_lh, h@u_rh, h@w_score,
// c@u_lc, c@u_rc) and cache them (bf16). Each pair at a higher level then only
// needs elementwise tanh-adds and a dot product.

#define BB 128
#define TT 32
#define DD 400
#define NCELLS 528

typedef __hip_bfloat16 bf16_t;

__device__ __forceinline__ int offs_of(int v) { return v * TT - (v * (v - 1)) / 2; }

__device__ __forceinline__ float bf2f(uint16_t u) {
    union { uint32_t i; float f; } v; v.i = ((uint32_t)u) << 16; return v.f;
}
__device__ __forceinline__ uint16_t f2bf(float f) {
    union { float f; uint32_t i; } v; v.f = f;
    uint32_t x = v.i;
    return (uint16_t)((x + 0x7fffu + ((x >> 16) & 1u)) >> 16);  // RNE
}

// Reduce two sums across a 256-thread block (4 waves of 64).
__device__ __forceinline__ void block_reduce2(float& a, float& b, float* sred) {
#pragma unroll
    for (int o = 32; o > 0; o >>= 1) { a += __shfl_down(a, o); b += __shfl_down(b, o); }
    int lane = threadIdx.x & 63, w = threadIdx.x >> 6;
    if (lane == 0) { sred[w] = a; sred[4 + w] = b; }
    __syncthreads();
    a = sred[0] + sred[1] + sred[2] + sred[3];
    b = sred[4] + sred[5] + sred[6] + sred[7];
    __syncthreads();
}

// Pack weight matrices into concatenated fp32 buffers:
// UH [400][1200] = [u_lh | u_rh | w_score], UC [400][800] = [u_lc | u_rc],
// WLEAF [400][800] = [w_leaf_h | w_leaf_c].
__global__ void pack_k(const float* __restrict__ u_lh, const float* __restrict__ u_rh,
                       const float* __restrict__ w_score, const float* __restrict__ u_lc,
                       const float* __restrict__ u_rc, const float* __restrict__ w_leaf_h,
                       const float* __restrict__ w_leaf_c,
                       float* __restrict__ UH, float* __restrict__ UC,
                       float* __restrict__ WLEAF) {
    int idx = blockIdx.x * blockDim.x + threadIdx.x;
    const int n1 = DD * 1200, n2 = DD * 800;
    if (idx < n1) {
        int d = idx / 1200, j = idx % 1200;
        float v = (j < 400) ? u_lh[d * DD + j]
                 : (j < 800) ? u_rh[d * DD + j - 400]
                             : w_score[d * DD + j - 800];
        UH[idx] = v;
    } else if (idx < n1 + n2) {
        int q = idx - n1; int d = q / 800, j = q % 800;
        UC[q] = (j < 400) ? u_lc[d * DD + j] : u_rc[d * DD + j - 400];
    } else if (idx < n1 + 2 * n2) {
        int q = idx - n1 - n2; int d = q / 800, j = q % 800;
        WLEAF[q] = (j < 400) ? w_leaf_h[d * DD + j] : w_leaf_c[d * DD + j - 400];
    }
}

// Generic fp32 GEMM, 128x128 tile, BK=8, 256 threads, 8x8 per thread.
// A rows gathered as: r -> b = r/Lcur, i = r%Lcur, addr = (b*a_stride + a_cellbase + i)*400.
// If outF != null: write fp32 at outF[r*Ncols + j].
// Else: write bf16 into transform planes: plane = plane0 + j/400, col j%400,
//       row offset (b*NCELLS + out_cellbase + i)*400.
__global__ __launch_bounds__(256)
void gemm_k(const float* __restrict__ A, int a_stride, int a_cellbase, int Lcur,
            const float* __restrict__ Bm, int Ncols,
            float* __restrict__ outF,
            bf16_t* __restrict__ outP, int plane0, int out_cellbase) {
    __shared__ float As[8][128];
    __shared__ float Bs[8][128];
    const int t = threadIdx.x;
    const int tile_m = blockIdx.y * 128;
    const int tile_n = blockIdx.x * 128;

    // A-load mapping: 2 threads per row, each loads a float4 of K.
    const int lm = t >> 1, lh = t & 1;
    const int arow = tile_m + lm;
    const int ab = arow / Lcur, ai = arow - ab * Lcur;
    const float* aptr = A + (size_t)(ab * a_stride + a_cellbase + ai) * DD + lh * 4;

    // B-load mapping: 32 threads per k-row, each a float4 of N.
    const int bk = t >> 5;
    const int bn = (t & 31) << 2;

    const int tx = t & 15, ty = t >> 4;
    float acc[8][8];
#pragma unroll
    for (int i = 0; i < 8; i++)
#pragma unroll
        for (int j = 0; j < 8; j++) acc[i][j] = 0.f;

    for (int k0 = 0; k0 < DD; k0 += 8) {
        float4 av = *(const float4*)(aptr + k0);
        float4 bv;
        const int jb = tile_n + bn;
        const float* bp = Bm + (size_t)(k0 + bk) * Ncols + jb;
        if (jb + 3 < Ncols) {
            bv = *(const float4*)bp;
        } else {
            bv.x = (jb + 0 < Ncols) ? bp[0] : 0.f;
            bv.y = (jb + 1 < Ncols) ? bp[1] : 0.f;
            bv.z = (jb + 2 < Ncols) ? bp[2] : 0.f;
            bv.w = (jb + 3 < Ncols) ? bp[3] : 0.f;
        }
        __syncthreads();
        As[lh * 4 + 0][lm] = av.x;
        As[lh * 4 + 1][lm] = av.y;
        As[lh * 4 + 2][lm] = av.z;
        As[lh * 4 + 3][lm] = av.w;
        *(float4*)&Bs[bk][bn] = bv;
        __syncthreads();
#pragma unroll
        for (int k = 0; k < 8; k++) {
            float a[8], b[8];
            *(float4*)&a[0] = *(const float4*)&As[k][ty * 4];
            *(float4*)&a[4] = *(const float4*)&As[k][64 + ty * 4];
            *(float4*)&b[0] = *(const float4*)&Bs[k][tx * 4];
            *(float4*)&b[4] = *(const float4*)&Bs[k][64 + tx * 4];
#pragma unroll
            for (int i = 0; i < 8; i++)
#pragma unroll
                for (int j = 0; j < 8; j++) acc[i][j] = fmaf(a[i], b[j], acc[i][j]);
        }
    }

    const size_t PL = (size_t)BB * NCELLS * DD;
#pragma unroll
    for (int ih = 0; ih < 2; ih++)
#pragma unroll
        for (int ii = 0; ii < 4; ii++) {
            int r = tile_m + ih * 64 + ty * 4 + ii;
            int rb = r / Lcur, ri = r - rb * Lcur;
#pragma unroll
            for (int jh = 0; jh < 2; jh++) {
                int colg = tile_n + jh * 64 + tx * 4;
                if (colg >= Ncols) continue;
                if (outF) {
                    float* o = outF + (size_t)r * Ncols + colg;
#pragma unroll
                    for (int jj = 0; jj < 4; jj++)
                        if (colg + jj < Ncols) o[jj] = acc[ih * 4 + ii][jh * 4 + jj];
                } else {
                    int pl = plane0 + colg / 400;
                    int jc = colg - (colg / 400) * 400;
                    uint16_t* o = (uint16_t*)(outP + (size_t)pl * PL
                                              + (size_t)(rb * NCELLS + out_cellbase + ri) * DD + jc);
#pragma unroll
                    for (int jj = 0; jj < 4; jj++)
                        if (colg + jj < Ncols) o[jj] = f2bf(acc[ih * 4 + ii][jh * 4 + jj]);
                }
            }
        }
}

// Leaf epilogue: tanh(pre + bias), unit-norm; write h0 -> chart, c0 -> ctmp, cs=0.
__global__ __launch_bounds__(256)
void leaf_norm_k(const float* __restrict__ PRE, const float* __restrict__ blh,
                 const float* __restrict__ blc, float* __restrict__ Hchart,
                 float* __restrict__ Ctmp, float* __restrict__ cs) {
    const int r = blockIdx.x;  // b*32 + t
    const int b = r >> 5, tt = r & 31;
    const int t = threadIdx.x;
    const int d = t * 2;
    float th0 = 0, th1 = 0, tc0 = 0, tc1 = 0;
    if (d < DD) {
        const float* p = PRE + (size_t)r * 800;
        th0 = tanhf(p[d] + blh[d]);
        th1 = tanhf(p[d + 1] + blh[d + 1]);
        tc0 = tanhf(p[400 + d] + blc[d]);
        tc1 = tanhf(p[400 + d + 1] + blc[d + 1]);
    }
    __shared__ float sred[8];
    float nh = th0 * th0 + th1 * th1, nc = tc0 * tc0 + tc1 * tc1;
    block_reduce2(nh, nc, sred);
    float rh = 1.f / fmaxf(sqrtf(nh), 1e-8f);
    float rc = 1.f / fmaxf(sqrtf(nc), 1e-8f);
    if (d < DD) {
        float* H = Hchart + (size_t)(b * NCELLS + tt) * DD;
        float* C = Ctmp + (size_t)(b * 32 + tt) * DD;
        H[d] = th0 * rh; H[d + 1] = th1 * rh;
        C[d] = tc0 * rc; C[d + 1] = tc1 * rc;
    }
    if (t == 0) cs[b * NCELLS + tt] = 0.f;
}

// One block per (b, i) cell of the current level:
//  phase 1: scores s_k = dot(g[lcell], h[rcell]) + cs[l] + cs[r]
//  phase 2: softmax over k (N = level values)
//  phase 3: h_agg = unit_norm(sum_k p_k tanh(a[l]+b2[r]+b_h)), same for c; s_agg.
__global__ __launch_bounds__(256)
void level_k(float* __restrict__ Hchart, float* __restrict__ Ctmp, float* __restrict__ cs,
             const bf16_t* __restrict__ planes,
             const float* __restrict__ b_h, const float* __restrict__ b_c, int level) {
    const size_t PL = (size_t)BB * NCELLS * DD;
    const int L = TT - level, N = level;
    const int blk = blockIdx.x;
    const int b = blk / L, i = blk - b * L;
    const int cell = offs_of(level) + i;
    const int t = threadIdx.x, lane = t & 63, w = t >> 6;
    __shared__ float sh_s[32], sh_p[32];
    __shared__ float sred[8];

    // Phase 1: each wave handles k = w, w+4, ...
    const uint16_t* G = (const uint16_t*)(planes + 2 * PL);
    for (int k = w; k < N; k += 4) {
        int lcell = offs_of(k) + i;
        int rcell = offs_of(level - k - 1) + i + k + 1;
        const uint16_t* g = G + (size_t)(b * NCELLS + lcell) * DD;
        const float* hr = Hchart + (size_t)(b * NCELLS + rcell) * DD;
        float s = 0.f;
        for (int d = lane; d < DD; d += 64) s += bf2f(g[d]) * hr[d];
#pragma unroll
        for (int o = 32; o > 0; o >>= 1) s += __shfl_down(s, o);
        if (lane == 0) sh_s[k] = s + cs[b * NCELLS + lcell] + cs[b * NCELLS + rcell];
    }
    __syncthreads();

    // Phase 2: softmax over N (tiny, single thread)
    if (t == 0) {
        float m = -1e30f;
        for (int k = 0; k < N; k++) m = fmaxf(m, sh_s[k]);
        float sum = 0.f;
        for (int k = 0; k < N; k++) { float e = expf(sh_s[k] - m); sh_p[k] = e; sum += e; }
        float inv = 1.f / sum, sagg = 0.f;
        for (int k = 0; k < N; k++) { sh_p[k] *= inv; sagg += sh_p[k] * sh_s[k]; }
        cs[b * NCELLS + cell] = sagg;
    }
    __syncthreads();

    // Phase 3: aggregate over pairs; thread owns dims (2t, 2t+1).
    float ha0 = 0, ha1 = 0, ca0 = 0, ca1 = 0;
    const int d = t * 2;
    if (d < DD) {
        const float bh0 = b_h[d], bh1 = b_h[d + 1], bc0 = b_c[d], bc1 = b_c[d + 1];
        const uint16_t* P0 = (const uint16_t*)planes;
        for (int k = 0; k < N; k++) {
            float p = sh_p[k];
            int lcell = offs_of(k) + i;
            int rcell = offs_of(level - k - 1) + i + k + 1;
            size_t lo = (size_t)(b * NCELLS + lcell) * DD + d;
            size_t ro = (size_t)(b * NCELLS + rcell) * DD + d;
            uint32_t av = *(const uint32_t*)(P0 + lo);            // plane 0: a (left)
            uint32_t bv = *(const uint32_t*)(P0 + PL + ro);       // plane 1: b2 (right)
            uint32_t ev = *(const uint32_t*)(P0 + 3 * PL + lo);   // plane 3: e (left)
            uint32_t fv = *(const uint32_t*)(P0 + 4 * PL + ro);   // plane 4: f (right)
            ha0 += p * tanhf(bf2f(av & 0xffff) + bf2f(bv & 0xffff) + bh0);
            ha1 += p * tanhf(bf2f(av >> 16) + bf2f(bv >> 16) + bh1);
            ca0 += p * tanhf(bf2f(ev & 0xffff) + bf2f(fv & 0xffff) + bc0);
            ca1 += p * tanhf(bf2f(ev >> 16) + bf2f(fv >> 16) + bc1);
        }
    }
    float nh = ha0 * ha0 + ha1 * ha1, nc = ca0 * ca0 + ca1 * ca1;
    block_reduce2(nh, nc, sred);
    float rh = 1.f / fmaxf(sqrtf(nh), 1e-8f);
    float rc = 1.f / fmaxf(sqrtf(nc), 1e-8f);
    if (d < DD) {
        float* H = Hchart + (size_t)(b * NCELLS + cell) * DD;
        float* C = Ctmp + (size_t)(b * 32 + i) * DD;
        H[d] = ha0 * rh; H[d + 1] = ha1 * rh;
        C[d] = ca0 * rc; C[d + 1] = ca1 * rc;
    }
}

extern "C" void kernel_launch(void* const* d_in, const int* in_sizes, int n_in,
                              void* d_out, int out_size, void* d_ws, size_t ws_size,
                              hipStream_t stream) {
    const float* x        = (const float*)d_in[0];
    const float* w_leaf_h = (const float*)d_in[1];
    const float* b_leaf_h = (const float*)d_in[2];
    const float* w_leaf_c = (const float*)d_in[3];
    const float* b_leaf_c = (const float*)d_in[4];
    const float* u_lh     = (const float*)d_in[5];
    const float* u_rh     = (const float*)d_in[6];
    const float* b_h      = (const float*)d_in[7];
    const float* u_lc     = (const float*)d_in[8];
    const float* u_rc     = (const float*)d_in[9];
    const float* b_c      = (const float*)d_in[10];
    const float* w_score  = (const float*)d_in[11];
    float* Hchart = (float*)d_out;

    const size_t PL = (size_t)BB * NCELLS * DD;
    char* p = (char*)d_ws;
    bf16_t* planes = (bf16_t*)p; p += 5 * PL * sizeof(bf16_t);          // 270.3 MB
    float* CS      = (float*)p;  p += (size_t)BB * NCELLS * sizeof(float);
    float* CTMP    = (float*)p;  p += (size_t)BB * 32 * DD * sizeof(float);
    float* UH      = (float*)p;  p += (size_t)DD * 1200 * sizeof(float);
    float* UC      = (float*)p;  p += (size_t)DD * 800 * sizeof(float);
    float* WLEAF   = (float*)p;  p += (size_t)DD * 800 * sizeof(float);
    float* PRE     = (float*)p;  p += (size_t)BB * TT * 800 * sizeof(float);

    {
        int total = DD * 1200 + DD * 800 + DD * 800;
        pack_k<<<(total + 255) / 256, 256, 0, stream>>>(u_lh, u_rh, w_score, u_lc, u_rc,
                                                        w_leaf_h, w_leaf_c, UH, UC, WLEAF);
    }
    // Leaf pre-activations: x(4096,400) @ WLEAF(400,800) -> PRE
    gemm_k<<<dim3(7, 32), 256, 0, stream>>>(x, 32, 0, 32, WLEAF, 800, PRE, nullptr, 0, 0);
    leaf_norm_k<<<BB * TT, 256, 0, stream>>>(PRE, b_leaf_h, b_leaf_c, Hchart, CTMP, CS);
    // Leaf transforms (h-side: planes 0..2; c-side: planes 3..4)
    gemm_k<<<dim3(10, 32), 256, 0, stream>>>(Hchart, NCELLS, 0, 32, UH, 1200, nullptr, planes, 0, 0);
    gemm_k<<<dim3(7, 32), 256, 0, stream>>>(CTMP, 32, 0, 32, UC, 800, nullptr, planes, 3, 0);

    int off = TT;
    for (int level = 1; level < TT; ++level) {
        int L = TT - level;
        level_k<<<BB * L, 256, 0, stream>>>(Hchart, CTMP, CS, planes, b_h, b_c, level);
        if (level < TT - 1) {  // last level's transforms are never consumed
            gemm_k<<<dim3(10, L), 256, 0, stream>>>(Hchart, NCELLS, off, L, UH, 1200,
                                                    nullptr, planes, 0, off);
            gemm_k<<<dim3(7, L), 256, 0, stream>>>(CTMP, 32, 0, L, UC, 800,
                                                   nullptr, planes, 3, off);
        }
        off += L;
    }
}

// Round 2
// 1733.247 us; speedup vs baseline: 3.5543x; 3.5543x over previous
//
#include <hip/hip_runtime.h>
#include <hip/hip_bf16.h>
#include <stdint.h>

// DIORA inside pass. B=128, T=32, D=400, ncells=528.
// Per-cell transform caching: each cell's h/c is transformed once by 5 matrices
// (u_lh,u_rh,w_score,u_lc,u_rc) via bf16 MFMA GEMM into cached planes; each
// pair at higher levels is then elementwise tanh-add + dot.

#define BB 128
#define TT 32
#define DD 400
#define NCELLS 528
#define NW 2000   // 5 planes x 400 output cols
#define KP 416    // K padded to 13*32

typedef __hip_bfloat16 bf16_t;
typedef __attribute__((ext_vector_type(8))) short s8v;
typedef __attribute__((ext_vector_type(4))) float f32x4;

__device__ __forceinline__ int offs_of(int v) { return v * TT - (v * (v - 1)) / 2; }

__device__ __forceinline__ float bf2f(uint16_t u) {
    union { uint32_t i; float f; } v; v.i = ((uint32_t)u) << 16; return v.f;
}
__device__ __forceinline__ uint16_t f2bf(float f) {
    union { float f; uint32_t i; } v; v.f = f;
    uint32_t x = v.i;
    return (uint16_t)((x + 0x7fffu + ((x >> 16) & 1u)) >> 16);  // RNE
}

__device__ __forceinline__ void block_reduce2(float& a, float& b, float* sred) {
#pragma unroll
    for (int o = 32; o > 0; o >>= 1) { a += __shfl_down(a, o); b += __shfl_down(b, o); }
    int lane = threadIdx.x & 63, w = threadIdx.x >> 6;
    if (lane == 0) { sred[w] = a; sred[4 + w] = b; }
    __syncthreads();
    a = sred[0] + sred[1] + sred[2] + sred[3];
    b = sred[4] + sred[5] + sred[6] + sred[7];
    __syncthreads();
}

// Pack: WT bf16 [2000][416] = transposed [u_lh|u_rh|w_score|u_lc|u_rc], k>=400 zero.
//       WLEAF fp32 [400][800] = [w_leaf_h | w_leaf_c].
__global__ void pack_k(const float* __restrict__ u_lh, const float* __restrict__ u_rh,
                       const float* __restrict__ w_score, const float* __restrict__ u_lc,
                       const float* __restrict__ u_rc, const float* __restrict__ w_leaf_h,
                       const float* __restrict__ w_leaf_c,
                       uint16_t* __restrict__ WT, float* __restrict__ WLEAF) {
    int idx = blockIdx.x * blockDim.x + threadIdx.x;
    const int nWT = NW * KP;
    if (idx < nWT) {
        int n = idx / KP, k = idx - n * KP;
        float v = 0.f;
        if (k < DD) {
            const float* src = (n < 400) ? u_lh : (n < 800) ? u_rh : (n < 1200) ? w_score
                               : (n < 1600) ? u_lc : u_rc;
            int nc = n % 400;
            v = src[k * DD + nc];
        }
        WT[idx] = f2bf(v);
    } else if (idx < nWT + DD * 800) {
        int q = idx - nWT; int d = q / 800, j = q % 800;
        WLEAF[q] = (j < 400) ? w_leaf_h[d * DD + j] : w_leaf_c[d * DD + j - 400];
    }
}

// fp32 GEMM for the leaf pre-activation only: A[4096][400] @ Bm[400][Ncols] -> outF.
__global__ __launch_bounds__(256)
void gemm_k(const float* __restrict__ A, const float* __restrict__ Bm, int Ncols,
            float* __restrict__ outF) {
    __shared__ float As[8][128];
    __shared__ float Bs[8][128];
    const int t = threadIdx.x;
    const int tile_m = blockIdx.y * 128;
    const int tile_n = blockIdx.x * 128;
    const int lm = t >> 1, lh = t & 1;
    const float* aptr = A + (size_t)(tile_m + lm) * DD + lh * 4;
    const int bk = t >> 5, bn = (t & 31) << 2;
    const int tx = t & 15, ty = t >> 4;
    float acc[8][8];
#pragma unroll
    for (int i = 0; i < 8; i++)
#pragma unroll
        for (int j = 0; j < 8; j++) acc[i][j] = 0.f;

    for (int k0 = 0; k0 < DD; k0 += 8) {
        float4 av = *(const float4*)(aptr + k0);
        float4 bv;
        const int jb = tile_n + bn;
        const float* bp = Bm + (size_t)(k0 + bk) * Ncols + jb;
        if (jb + 3 < Ncols) {
            bv = *(const float4*)bp;
        } else {
            bv.x = (jb + 0 < Ncols) ? bp[0] : 0.f;
            bv.y = (jb + 1 < Ncols) ? bp[1] : 0.f;
            bv.z = (jb + 2 < Ncols) ? bp[2] : 0.f;
            bv.w = (jb + 3 < Ncols) ? bp[3] : 0.f;
        }
        __syncthreads();
        As[lh * 4 + 0][lm] = av.x;
        As[lh * 4 + 1][lm] = av.y;
        As[lh * 4 + 2][lm] = av.z;
        As[lh * 4 + 3][lm] = av.w;
        *(float4*)&Bs[bk][bn] = bv;
        __syncthreads();
#pragma unroll
        for (int k = 0; k < 8; k++) {
            float a[8], b[8];
            *(float4*)&a[0] = *(const float4*)&As[k][ty * 4];
            *(float4*)&a[4] = *(const float4*)&As[k][64 + ty * 4];
            *(float4*)&b[0] = *(const float4*)&Bs[k][tx * 4];
            *(float4*)&b[4] = *(const float4*)&Bs[k][64 + tx * 4];
#pragma unroll
            for (int i = 0; i < 8; i++)
#pragma unroll
                for (int j = 0; j < 8; j++) acc[i][j] = fmaf(a[i], b[j], acc[i][j]);
        }
    }
#pragma unroll
    for (int ih = 0; ih < 2; ih++)
#pragma unroll
        for (int ii = 0; ii < 4; ii++) {
            int r = tile_m + ih * 64 + ty * 4 + ii;
#pragma unroll
            for (int jh = 0; jh < 2; jh++) {
                int colg = tile_n + jh * 64 + tx * 4;
                if (colg >= Ncols) continue;
                float* o = outF + (size_t)r * Ncols + colg;
#pragma unroll
                for (int jj = 0; jj < 4; jj++)
                    if (colg + jj < Ncols) o[jj] = acc[ih * 4 + ii][jh * 4 + jj];
            }
        }
}

// MFMA bf16 transform GEMM. M = 128*Lcur rows (b-major: r -> rb=r/Lcur, ri=r%Lcur).
// Cols 0..1199: A = HB cell rows (rb*NCELLS+cellbase+ri); cols 1200..1999: A = CB
// rows (rb*32+ri). Output bf16 planes[n/400] at row (rb*NCELLS+cellbase+ri), col n%400.
// Block: 128x80 tile, BK=32, 4 waves x (2 m-tiles x 5 n-tiles) of 16x16x32 MFMA.
__global__ __launch_bounds__(256)
void tgemm_k(const uint16_t* __restrict__ HB, const uint16_t* __restrict__ CB,
             const uint16_t* __restrict__ WT, uint16_t* __restrict__ planes,
             int Lcur, int cellbase) {
    __shared__ short As[128][40];  // padded stride (2-way bank alias = free)
    __shared__ short Ws[80][40];
    const int t = threadIdx.x, lane = t & 63, w = t >> 6;
    const int n0 = blockIdx.x * 80;
    const int tile_m = blockIdx.y * 128;
    const bool cside = (n0 >= 1200);
    const size_t PL = (size_t)BB * NCELLS * DD;

    // A staging: thread t loads rows (t>>2) and (t>>2)+64, 16B at col 8*(t&3).
    const int arow_l = t >> 2, asub = t & 3;
    const uint16_t* aptr[2];
#pragma unroll
    for (int p = 0; p < 2; p++) {
        int gr = tile_m + arow_l + 64 * p;
        int rb = gr / Lcur, ri = gr - rb * Lcur;
        const uint16_t* base = cside ? CB + (size_t)(rb * 32 + ri) * DD
                                     : HB + (size_t)(rb * NCELLS + cellbase + ri) * DD;
        aptr[p] = base + asub * 8;
    }
    // W staging: chunk t -> row t>>2 (0..63); t<64 also chunk 256+t -> row 64+(t>>2).
    const uint16_t* wptr0 = WT + (size_t)(n0 + (t >> 2)) * KP + (t & 3) * 8;
    const uint16_t* wptr1 = WT + (size_t)(n0 + 64 + (t >> 2)) * KP + (t & 3) * 8;

    const int frow = lane & 15, kcol = (lane >> 4) * 8;
    f32x4 acc[2][5];
#pragma unroll
    for (int mi = 0; mi < 2; mi++)
#pragma unroll
        for (int ni = 0; ni < 5; ni++) acc[mi][ni] = (f32x4)(0.f);

    for (int k0 = 0; k0 < KP; k0 += 32) {
        s8v av0 = *(const s8v*)(aptr[0] + k0);
        s8v av1 = *(const s8v*)(aptr[1] + k0);
        s8v wv0 = *(const s8v*)(wptr0 + k0);
        s8v wv1;
        if (t < 64) wv1 = *(const s8v*)(wptr1 + k0);
        __syncthreads();
        *(s8v*)&As[arow_l][asub * 8] = av0;
        *(s8v*)&As[arow_l + 64][asub * 8] = av1;
        *(s8v*)&Ws[t >> 2][(t & 3) * 8] = wv0;
        if (t < 64) *(s8v*)&Ws[64 + (t >> 2)][(t & 3) * 8] = wv1;
        __syncthreads();
        s8v a0 = *(const s8v*)&As[32 * w + frow][kcol];
        s8v a1 = *(const s8v*)&As[32 * w + 16 + frow][kcol];
#pragma unroll
        for (int ni = 0; ni < 5; ni++) {
            s8v bv = *(const s8v*)&Ws[16 * ni + frow][kcol];
            acc[0][ni] = __builtin_amdgcn_mfma_f32_16x16x32_bf16(a0, bv, acc[0][ni], 0, 0, 0);
            acc[1][ni] = __builtin_amdgcn_mfma_f32_16x16x32_bf16(a1, bv, acc[1][ni], 0, 0, 0);
        }
    }

    const int plane = n0 / 400, ncbase = n0 % 400;
    uint16_t* pbase = planes + (size_t)plane * PL;
#pragma unroll
    for (int mi = 0; mi < 2; mi++) {
        int rbase = tile_m + 32 * w + 16 * mi + 4 * (lane >> 4);
#pragma unroll
        for (int i = 0; i < 4; i++) {
            int gr = rbase + i;
            int rb = gr / Lcur, ri = gr - rb * Lcur;
            uint16_t* orow = pbase + (size_t)(rb * NCELLS + cellbase + ri) * DD
                             + ncbase + (lane & 15);
#pragma unroll
            for (int ni = 0; ni < 5; ni++) orow[16 * ni] = f2bf(acc[mi][ni][i]);
        }
    }
}

// Leaf epilogue: tanh(pre + bias), unit-norm; h -> Hchart fp32 + HB bf16, c -> CB bf16.
__global__ __launch_bounds__(256)
void leaf_norm_k(const float* __restrict__ PRE, const float* __restrict__ blh,
                 const float* __restrict__ blc, float* __restrict__ Hchart,
                 uint16_t* __restrict__ HB, uint16_t* __restrict__ CB,
                 float* __restrict__ cs) {
    const int r = blockIdx.x;  // b*32 + t
    const int b = r >> 5, tt = r & 31;
    const int t = threadIdx.x;
    const int d = t * 2;
    float th0 = 0, th1 = 0, tc0 = 0, tc1 = 0;
    if (d < DD) {
        const float* p = PRE + (size_t)r * 800;
        th0 = tanhf(p[d] + blh[d]);
        th1 = tanhf(p[d + 1] + blh[d + 1]);
        tc0 = tanhf(p[400 + d] + blc[d]);
        tc1 = tanhf(p[400 + d + 1] + blc[d + 1]);
    }
    __shared__ float sred[8];
    float nh = th0 * th0 + th1 * th1, nc = tc0 * tc0 + tc1 * tc1;
    block_reduce2(nh, nc, sred);
    float rh = 1.f / fmaxf(sqrtf(nh), 1e-8f);
    float rc = 1.f / fmaxf(sqrtf(nc), 1e-8f);
    if (d < DD) {
        size_t ho = (size_t)(b * NCELLS + tt) * DD + d;
        float h0 = th0 * rh, h1 = th1 * rh, c0 = tc0 * rc, c1 = tc1 * rc;
        Hchart[ho] = h0; Hchart[ho + 1] = h1;
        *(uint32_t*)(HB + ho) = (uint32_t)f2bf(h0) | ((uint32_t)f2bf(h1) << 16);
        *(uint32_t*)(CB + (size_t)(b * 32 + tt) * DD + d) =
            (uint32_t)f2bf(c0) | ((uint32_t)f2bf(c1) << 16);
    }
    if (t == 0) cs[b * NCELLS + tt] = 0.f;
}

// One block per (b,i) cell of the level: scores -> softmax -> aggregate.
__global__ __launch_bounds__(256)
void level_k(float* __restrict__ Hchart, uint16_t* __restrict__ HB,
             uint16_t* __restrict__ CB, float* __restrict__ cs,
             const uint16_t* __restrict__ planes,
             const float* __restrict__ b_h, const float* __restrict__ b_c, int level) {
    const size_t PL = (size_t)BB * NCELLS * DD;
    const int L = TT - level, N = level;
    const int blk = blockIdx.x;
    const int b = blk / L, i = blk - b * L;
    const int cell = offs_of(level) + i;
    const int t = threadIdx.x, lane = t & 63, w = t >> 6;
    __shared__ float sh_s[32], sh_p[32];
    __shared__ float sred[8];

    // Phase 1: scores, bf16 g . bf16 h
    const uint16_t* G = planes + 2 * PL;
    for (int k = w; k < N; k += 4) {
        int lcell = offs_of(k) + i;
        int rcell = offs_of(level - k - 1) + i + k + 1;
        const uint16_t* g = G + (size_t)(b * NCELLS + lcell) * DD;
        const uint16_t* hr = HB + (size_t)(b * NCELLS + rcell) * DD;
        float s = 0.f;
        for (int d = lane; d < DD; d += 64) s += bf2f(g[d]) * bf2f(hr[d]);
#pragma unroll
        for (int o = 32; o > 0; o >>= 1) s += __shfl_down(s, o);
        if (lane == 0) sh_s[k] = s + cs[b * NCELLS + lcell] + cs[b * NCELLS + rcell];
    }
    __syncthreads();

    // Phase 2: softmax over N (tiny)
    if (t == 0) {
        float m = -1e30f;
        for (int k = 0; k < N; k++) m = fmaxf(m, sh_s[k]);
        float sum = 0.f;
        for (int k = 0; k < N; k++) { float e = expf(sh_s[k] - m); sh_p[k] = e; sum += e; }
        float inv = 1.f / sum, sagg = 0.f;
        for (int k = 0; k < N; k++) { sh_p[k] *= inv; sagg += sh_p[k] * sh_s[k]; }
        cs[b * NCELLS + cell] = sagg;
    }
    __syncthreads();

    // Phase 3: aggregate; thread owns dims (2t, 2t+1).
    float ha0 = 0, ha1 = 0, ca0 = 0, ca1 = 0;
    const int d = t * 2;
    if (d < DD) {
        const float bh0 = b_h[d], bh1 = b_h[d + 1], bc0 = b_c[d], bc1 = b_c[d + 1];
        for (int k = 0; k < N; k++) {
            float p = sh_p[k];
            int lcell = offs_of(k) + i;
            int rcell = offs_of(level - k - 1) + i + k + 1;
            size_t lo = (size_t)(b * NCELLS + lcell) * DD + d;
            size_t ro = (size_t)(b * NCELLS + rcell) * DD + d;
            uint32_t av = *(const uint32_t*)(planes + lo);           // plane 0: a (left)
            uint32_t bv = *(const uint32_t*)(planes + PL + ro);      // plane 1: b2 (right)
            uint32_t ev = *(const uint32_t*)(planes + 3 * PL + lo);  // plane 3: e (left)
            uint32_t fv = *(const uint32_t*)(planes + 4 * PL + ro);  // plane 4: f (right)
            ha0 += p * tanhf(bf2f(av & 0xffff) + bf2f(bv & 0xffff) + bh0);
            ha1 += p * tanhf(bf2f(av >> 16) + bf2f(bv >> 16) + bh1);
            ca0 += p * tanhf(bf2f(ev & 0xffff) + bf2f(fv & 0xffff) + bc0);
            ca1 += p * tanhf(bf2f(ev >> 16) + bf2f(fv >> 16) + bc1);
        }
    }
    float nh = ha0 * ha0 + ha1 * ha1, nc = ca0 * ca0 + ca1 * ca1;
    block_reduce2(nh, nc, sred);
    float rh = 1.f / fmaxf(sqrtf(nh), 1e-8f);
    float rc = 1.f / fmaxf(sqrtf(nc), 1e-8f);
    if (d < DD) {
        float h0 = ha0 * rh, h1 = ha1 * rh, c0 = ca0 * rc, c1 = ca1 * rc;
        size_t ho = (size_t)(b * NCELLS + cell) * DD + d;
        Hchart[ho] = h0; Hchart[ho + 1] = h1;
        *(uint32_t*)(HB + ho) = (uint32_t)f2bf(h0) | ((uint32_t)f2bf(h1) << 16);
        *(uint32_t*)(CB + (size_t)(b * 32 + i) * DD + d) =
            (uint32_t)f2bf(c0) | ((uint32_t)f2bf(c1) << 16);
    }
}

extern "C" void kernel_launch(void* const* d_in, const int* in_sizes, int n_in,
                              void* d_out, int out_size, void* d_ws, size_t ws_size,
                              hipStream_t stream) {
    const float* x        = (const float*)d_in[0];
    const float* b_leaf_h = (const float*)d_in[2];
    const float* b_leaf_c = (const float*)d_in[4];
    const float* u_lh     = (const float*)d_in[5];
    const float* u_rh     = (const float*)d_in[6];
    const float* b_h      = (const float*)d_in[7];
    const float* u_lc     = (const float*)d_in[8];
    const float* u_rc     = (const float*)d_in[9];
    const float* b_c      = (const float*)d_in[10];
    const float* w_score  = (const float*)d_in[11];
    const float* w_leaf_h = (const float*)d_in[1];
    const float* w_leaf_c = (const float*)d_in[3];
    float* Hchart = (float*)d_out;

    const size_t PL = (size_t)BB * NCELLS * DD;
    char* p = (char*)d_ws;
    uint16_t* planes = (uint16_t*)p; p += 5 * PL * sizeof(uint16_t);   // 270.3 MB
    uint16_t* HB     = (uint16_t*)p; p += PL * sizeof(uint16_t) + 64;  // 54.1 MB (+pad)
    uint16_t* CB     = (uint16_t*)p; p += (size_t)BB * 32 * DD * sizeof(uint16_t) + 64;
    float* CS        = (float*)p;    p += (size_t)BB * NCELLS * sizeof(float);
    uint16_t* WT     = (uint16_t*)p; p += (size_t)NW * KP * sizeof(uint16_t);
    float* WLEAF     = (float*)p;    p += (size_t)DD * 800 * sizeof(float);
    float* PRE       = (float*)planes;  // alias: dead before any plane write

    {
        int total = NW * KP + DD * 800;
        pack_k<<<(total + 255) / 256, 256, 0, stream>>>(u_lh, u_rh, w_score, u_lc, u_rc,
                                                        w_leaf_h, w_leaf_c, WT, WLEAF);
    }
    gemm_k<<<dim3(7, 32), 256, 0, stream>>>(x, WLEAF, 800, PRE);
    leaf_norm_k<<<BB * TT, 256, 0, stream>>>(PRE, b_leaf_h, b_leaf_c, Hchart, HB, CB, CS);
    tgemm_k<<<dim3(25, 32), 256, 0, stream>>>(HB, CB, WT, planes, 32, 0);

    int off = TT;
    for (int level = 1; level < TT; ++level) {
        int L = TT - level;
        level_k<<<BB * L, 256, 0, stream>>>(Hchart, HB, CB, CS, planes, b_h, b_c, level);
        if (level < TT - 1) {
            tgemm_k<<<dim3(25, L), 256, 0, stream>>>(HB, CB, WT, planes, L, off);
        }
        off += L;
    }
}

// Round 4
// 1610.530 us; speedup vs baseline: 3.8251x; 1.0762x over previous
//
#include <hip/hip_runtime.h>
#include <hip/hip_bf16.h>
#include <stdint.h>

// DIORA inside pass. B=128, T=32, D=400, ncells=528.
// Per-cell transform caching via bf16 MFMA GEMM into interleaved planes:
//   LP[cell][2j+0]=a_j (h@u_lh), LP[cell][2j+1]=e_j (c@u_lc)
//   RP[cell][2j+0]=b2_j (h@u_rh), RP[cell][2j+1]=f_j (c@u_rc)
//   G [cell][j]   =g_j (h@w_score)
// level_k then streams 8B-vectorized pair rows (score dot + tanh-aggregate).

#define BB 128
#define TT 32
#define DD 400
#define NCELLS 528
#define NW 2000   // 5 weight blocks x 400 output cols
#define KP 416    // K padded to 13*32

typedef __hip_bfloat16 bf16_t;
typedef __attribute__((ext_vector_type(8))) short s8v;
typedef __attribute__((ext_vector_type(4))) float f32x4;

__device__ __forceinline__ int offs_of(int v) { return v * TT - (v * (v - 1)) / 2; }

// Bit-cast: bits ALREADY positioned as a float's bit pattern.
__device__ __forceinline__ float asf(uint32_t bits) {
    union { uint32_t i; float f; } v; v.i = bits; return v.f;
}
__device__ __forceinline__ uint16_t f2bf(float f) {
    union { float f; uint32_t i; } v; v.f = f;
    uint32_t x = v.i;
    return (uint16_t)((x + 0x7fffu + ((x >> 16) & 1u)) >> 16);  // RNE
}

__device__ __forceinline__ void block_reduce2(float& a, float& b, float* sred) {
#pragma unroll
    for (int o = 32; o > 0; o >>= 1) { a += __shfl_down(a, o); b += __shfl_down(b, o); }
    int lane = threadIdx.x & 63, w = threadIdx.x >> 6;
    if (lane == 0) { sred[w] = a; sred[4 + w] = b; }
    __syncthreads();
    a = sred[0] + sred[1] + sred[2] + sred[3];
    b = sred[4] + sred[5] + sred[6] + sred[7];
    __syncthreads();
}

// Pack: WT bf16 [2000][416] = transposed [u_lh|u_rh|w_score|u_lc|u_rc] (k>=400 zero);
//       WLT bf16 [800][416] = transposed [w_leaf_h|w_leaf_c];
//       XB bf16 [4096][416] = x rows, k-padded with zeros.
__global__ void pack_k(const float* __restrict__ u_lh, const float* __restrict__ u_rh,
                       const float* __restrict__ w_score, const float* __restrict__ u_lc,
                       const float* __restrict__ u_rc, const float* __restrict__ w_leaf_h,
                       const float* __restrict__ w_leaf_c, const float* __restrict__ x,
                       uint16_t* __restrict__ WT, uint16_t* __restrict__ WLT,
                       uint16_t* __restrict__ XB) {
    int idx = blockIdx.x * blockDim.x + threadIdx.x;
    const int nWT = NW * KP, nWLT = 800 * KP, nXB = 4096 * KP;
    if (idx < nWT) {
        int n = idx / KP, k = idx - n * KP;
        float v = 0.f;
        if (k < DD) {
            const float* src = (n < 400) ? u_lh : (n < 800) ? u_rh : (n < 1200) ? w_score
                               : (n < 1600) ? u_lc : u_rc;
            v = src[k * DD + (n % 400)];
        }
        WT[idx] = f2bf(v);
    } else if (idx < nWT + nWLT) {
        int q = idx - nWT; int n = q / KP, k = q - n * KP;
        float v = 0.f;
        if (k < DD) v = (n < 400) ? w_leaf_h[k * DD + n] : w_leaf_c[k * DD + (n - 400)];
        WLT[q] = f2bf(v);
    } else if (idx < nWT + nWLT + nXB) {
        int q = idx - nWT - nWLT; int r = q / KP, k = q - r * KP;
        XB[q] = f2bf(k < DD ? x[(size_t)r * DD + k] : 0.f);
    }
}

// MFMA bf16 GEMM, 128x80 tile, BK=32, 4 waves x (2m x 5n) 16x16x32 MFMA.
// mode 0 (transform): A = HB cells (n0<1200) or CB (n0>=1200); rows map
//   gr -> rb=gr/Lcur, ri=gr%Lcur, cell row rb*NCELLS+cellbase+ri.
//   Epilogue scatters into LP/RP/G per 400-col segment.
// mode 1 (leaf): A = XB + gr*416 (Ncols=800, W=WLT); writes fp32 PRE[gr*800+col].
__global__ __launch_bounds__(256)
void tgemm_k(const uint16_t* __restrict__ HB, const uint16_t* __restrict__ CB,
             const uint16_t* __restrict__ WT,
             uint16_t* __restrict__ LP, uint16_t* __restrict__ RP, uint16_t* __restrict__ G,
             float* __restrict__ PREout, int mode, int Lcur, int cellbase) {
    __shared__ short As[128][40];  // padded stride (2-way bank alias = free)
    __shared__ short Ws[80][40];
    const int t = threadIdx.x, lane = t & 63, w = t >> 6;
    const int n0 = blockIdx.x * 80;
    const int tile_m = blockIdx.y * 128;
    const bool cside = (mode == 0) && (n0 >= 1200);

    // A staging: thread t loads rows (t>>2) and (t>>2)+64, 16B at col 8*(t&3).
    const int arow_l = t >> 2, asub = t & 3;
    const uint16_t* aptr[2];
#pragma unroll
    for (int p = 0; p < 2; p++) {
        int gr = tile_m + arow_l + 64 * p;
        const uint16_t* base;
        if (mode == 1) {
            base = HB + (size_t)gr * KP;  // HB slot carries XB in mode 1
        } else {
            int rb = gr / Lcur, ri = gr - rb * Lcur;
            base = cside ? CB + (size_t)(rb * 32 + ri) * DD
                         : HB + (size_t)(rb * NCELLS + cellbase + ri) * DD;
        }
        aptr[p] = base + asub * 8;
    }
    const uint16_t* wptr0 = WT + (size_t)(n0 + (t >> 2)) * KP + (t & 3) * 8;
    const uint16_t* wptr1 = WT + (size_t)(n0 + 64 + (t >> 2)) * KP + (t & 3) * 8;

    const int frow = lane & 15, kcol = (lane >> 4) * 8;
    f32x4 acc[2][5];
#pragma unroll
    for (int mi = 0; mi < 2; mi++)
#pragma unroll
        for (int ni = 0; ni < 5; ni++) acc[mi][ni] = (f32x4)(0.f);

    for (int k0 = 0; k0 < KP; k0 += 32) {
        s8v av0 = *(const s8v*)(aptr[0] + k0);
        s8v av1 = *(const s8v*)(aptr[1] + k0);
        s8v wv0 = *(const s8v*)(wptr0 + k0);
        s8v wv1;
        if (t < 64) wv1 = *(const s8v*)(wptr1 + k0);
        __syncthreads();
        *(s8v*)&As[arow_l][asub * 8] = av0;
        *(s8v*)&As[arow_l + 64][asub * 8] = av1;
        *(s8v*)&Ws[t >> 2][(t & 3) * 8] = wv0;
        if (t < 64) *(s8v*)&Ws[64 + (t >> 2)][(t & 3) * 8] = wv1;
        __syncthreads();
        s8v a0 = *(const s8v*)&As[32 * w + frow][kcol];
        s8v a1 = *(const s8v*)&As[32 * w + 16 + frow][kcol];
#pragma unroll
        for (int ni = 0; ni < 5; ni++) {
            s8v bv = *(const s8v*)&Ws[16 * ni + frow][kcol];
            acc[0][ni] = __builtin_amdgcn_mfma_f32_16x16x32_bf16(a0, bv, acc[0][ni], 0, 0, 0);
            acc[1][ni] = __builtin_amdgcn_mfma_f32_16x16x32_bf16(a1, bv, acc[1][ni], 0, 0, 0);
        }
    }

    // Epilogue
    const int seg = n0 / 400, ncb = n0 % 400;       // mode 0 only
    uint16_t* tb = (seg == 2) ? G : (seg == 0 || seg == 3) ? LP : RP;
    const int slot = (seg >= 3) ? 1 : 0;
#pragma unroll
    for (int mi = 0; mi < 2; mi++) {
        int rbase = tile_m + 32 * w + 16 * mi + 4 * (lane >> 4);
#pragma unroll
        for (int i = 0; i < 4; i++) {
            int gr = rbase + i;
            if (mode == 1) {
                float* o = PREout + (size_t)gr * 800 + n0 + frow;
#pragma unroll
                for (int ni = 0; ni < 5; ni++) o[16 * ni] = acc[mi][ni][i];
            } else {
                int rb = gr / Lcur, ri = gr - rb * Lcur;
                size_t row = (size_t)(rb * NCELLS + cellbase + ri);
                if (seg == 2) {
                    uint16_t* o = tb + row * 400 + ncb + frow;
#pragma unroll
                    for (int ni = 0; ni < 5; ni++) o[16 * ni] = f2bf(acc[mi][ni][i]);
                } else {
                    uint16_t* o = tb + row * 800 + 2 * (ncb + frow) + slot;
#pragma unroll
                    for (int ni = 0; ni < 5; ni++) o[32 * ni] = f2bf(acc[mi][ni][i]);
                }
            }
        }
    }
}

// Leaf epilogue: tanh(pre + bias), unit-norm; h -> Hchart fp32 + HB bf16, c -> CB bf16.
__global__ __launch_bounds__(256)
void leaf_norm_k(const float* __restrict__ PRE, const float* __restrict__ blh,
                 const float* __restrict__ blc, float* __restrict__ Hchart,
                 uint16_t* __restrict__ HB, uint16_t* __restrict__ CB,
                 float* __restrict__ cs) {
    const int r = blockIdx.x;  // b*32 + t
    const int b = r >> 5, tt = r & 31;
    const int t = threadIdx.x;
    const int d = t * 2;
    float th0 = 0, th1 = 0, tc0 = 0, tc1 = 0;
    if (d < DD) {
        const float* p = PRE + (size_t)r * 800;
        th0 = tanhf(p[d] + blh[d]);
        th1 = tanhf(p[d + 1] + blh[d + 1]);
        tc0 = tanhf(p[400 + d] + blc[d]);
        tc1 = tanhf(p[400 + d + 1] + blc[d + 1]);
    }
    __shared__ float sred[8];
    float nh = th0 * th0 + th1 * th1, nc = tc0 * tc0 + tc1 * tc1;
    block_reduce2(nh, nc, sred);
    float rh = 1.f / fmaxf(sqrtf(nh), 1e-8f);
    float rc = 1.f / fmaxf(sqrtf(nc), 1e-8f);
    if (d < DD) {
        size_t ho = (size_t)(b * NCELLS + tt) * DD + d;
        float h0 = th0 * rh, h1 = th1 * rh, c0 = tc0 * rc, c1 = tc1 * rc;
        Hchart[ho] = h0; Hchart[ho + 1] = h1;
        *(uint32_t*)(HB + ho) = (uint32_t)f2bf(h0) | ((uint32_t)f2bf(h1) << 16);
        *(uint32_t*)(CB + (size_t)(b * 32 + tt) * DD + d) =
            (uint32_t)f2bf(c0) | ((uint32_t)f2bf(c1) << 16);
    }
    if (t == 0) cs[b * NCELLS + tt] = 0.f;
}

// One block per (b,i) cell of the level: scores -> softmax -> aggregate.
__global__ __launch_bounds__(256)
void level_k(float* __restrict__ Hchart, uint16_t* __restrict__ HB,
             uint16_t* __restrict__ CB, float* __restrict__ cs,
             const uint16_t* __restrict__ LP, const uint16_t* __restrict__ RP,
             const uint16_t* __restrict__ G,
             const float* __restrict__ b_h, const float* __restrict__ b_c, int level) {
    const int L = TT - level, N = level;
    const int blk = blockIdx.x;
    const int b = blk / L, i = blk - b * L;
    const int cell = offs_of(level) + i;
    const int t = threadIdx.x, lane = t & 63, w = t >> 6;
    __shared__ float sh_s[32], sh_p[32];
    __shared__ float sred[8];

    // Phase 1: scores s_k = g[lcell] . h[rcell] (+ child scores)
    for (int k = w; k < N; k += 4) {
        int lcell = offs_of(k) + i;
        int rcell = offs_of(level - k - 1) + i + k + 1;
        const uint32_t* g = (const uint32_t*)(G + (size_t)(b * NCELLS + lcell) * DD);
        const uint32_t* hr = (const uint32_t*)(HB + (size_t)(b * NCELLS + rcell) * DD);
        float s = 0.f;
        for (int d2 = lane; d2 < 200; d2 += 64) {
            uint32_t gv = g[d2], hv = hr[d2];
            s += asf(gv << 16) * asf(hv << 16)
               + asf(gv & 0xffff0000u) * asf(hv & 0xffff0000u);
        }
#pragma unroll
        for (int o = 32; o > 0; o >>= 1) s += __shfl_down(s, o);
        if (lane == 0) sh_s[k] = s + cs[b * NCELLS + lcell] + cs[b * NCELLS + rcell];
    }
    __syncthreads();

    // Phase 2: softmax over N (tiny)
    if (t == 0) {
        float m = -1e30f;
        for (int k = 0; k < N; k++) m = fmaxf(m, sh_s[k]);
        float sum = 0.f;
        for (int k = 0; k < N; k++) { float e = expf(sh_s[k] - m); sh_p[k] = e; sum += e; }
        float inv = 1.f / sum, sagg = 0.f;
        for (int k = 0; k < N; k++) { sh_p[k] *= inv; sagg += sh_p[k] * sh_s[k]; }
        cs[b * NCELLS + cell] = sagg;
    }
    __syncthreads();

    // Phase 3: aggregate; thread owns dims (2t, 2t+1); 8B loads from LP/RP.
    float ha0 = 0, ha1 = 0, ca0 = 0, ca1 = 0;
    const int d = t * 2;
    if (d < DD) {
        const float bh0 = b_h[d], bh1 = b_h[d + 1], bc0 = b_c[d], bc1 = b_c[d + 1];
        const uint16_t* lpb = LP + (size_t)(b * NCELLS) * 800 + 2 * d;
        const uint16_t* rpb = RP + (size_t)(b * NCELLS) * 800 + 2 * d;
        for (int k = 0; k < N; k++) {
            float p = sh_p[k];
            int lcell = offs_of(k) + i;
            int rcell = offs_of(level - k - 1) + i + k + 1;
            uint2 lv = *(const uint2*)(lpb + (size_t)lcell * 800);
            uint2 rv = *(const uint2*)(rpb + (size_t)rcell * 800);
            // lv.x = a_d | e_d<<16 ; lv.y = a_{d+1} | e_{d+1}<<16 (rv: b2,f)
            ha0 += p * tanhf(asf(lv.x << 16) + asf(rv.x << 16) + bh0);
            ca0 += p * tanhf(asf(lv.x & 0xffff0000u) + asf(rv.x & 0xffff0000u) + bc0);
            ha1 += p * tanhf(asf(lv.y << 16) + asf(rv.y << 16) + bh1);
            ca1 += p * tanhf(asf(lv.y & 0xffff0000u) + asf(rv.y & 0xffff0000u) + bc1);
        }
    }
    float nh = ha0 * ha0 + ha1 * ha1, nc = ca0 * ca0 + ca1 * ca1;
    block_reduce2(nh, nc, sred);
    float rh = 1.f / fmaxf(sqrtf(nh), 1e-8f);
    float rc = 1.f / fmaxf(sqrtf(nc), 1e-8f);
    if (d < DD) {
        float h0 = ha0 * rh, h1 = ha1 * rh, c0 = ca0 * rc, c1 = ca1 * rc;
        size_t ho = (size_t)(b * NCELLS + cell) * DD + d;
        Hchart[ho] = h0; Hchart[ho + 1] = h1;
        *(uint32_t*)(HB + ho) = (uint32_t)f2bf(h0) | ((uint32_t)f2bf(h1) << 16);
        *(uint32_t*)(CB + (size_t)(b * 32 + i) * DD + d) =
            (uint32_t)f2bf(c0) | ((uint32_t)f2bf(c1) << 16);
    }
}

extern "C" void kernel_launch(void* const* d_in, const int* in_sizes, int n_in,
                              void* d_out, int out_size, void* d_ws, size_t ws_size,
                              hipStream_t stream) {
    const float* x        = (const float*)d_in[0];
    const float* w_leaf_h = (const float*)d_in[1];
    const float* b_leaf_h = (const float*)d_in[2];
    const float* w_leaf_c = (const float*)d_in[3];
    const float* b_leaf_c = (const float*)d_in[4];
    const float* u_lh     = (const float*)d_in[5];
    const float* u_rh     = (const float*)d_in[6];
    const float* b_h      = (const float*)d_in[7];
    const float* u_lc     = (const float*)d_in[8];
    const float* u_rc     = (const float*)d_in[9];
    const float* b_c      = (const float*)d_in[10];
    const float* w_score  = (const float*)d_in[11];
    float* Hchart = (float*)d_out;

    const size_t PL = (size_t)BB * NCELLS * DD;
    char* p = (char*)d_ws;
    uint16_t* LP = (uint16_t*)p; p += 2 * PL * sizeof(uint16_t);        // 108.2 MB
    uint16_t* RP = (uint16_t*)p; p += 2 * PL * sizeof(uint16_t);        // 108.2 MB
    uint16_t* G  = (uint16_t*)p; p += PL * sizeof(uint16_t);            // 54.1 MB
    uint16_t* HB = (uint16_t*)p; p += PL * sizeof(uint16_t) + 64;       // 54.1 MB (+pad)
    uint16_t* CB = (uint16_t*)p; p += (size_t)BB * 32 * DD * sizeof(uint16_t) + 64;
    float* CS    = (float*)p;    p += (size_t)BB * NCELLS * sizeof(float);
    uint16_t* WT = (uint16_t*)p; p += (size_t)NW * KP * sizeof(uint16_t);
    // Aliases (dead before their hosts' first writes):
    float* PRE    = (float*)LP;            // dead before first LP write
    uint16_t* WLT = RP;                    // dead before first RP write
    uint16_t* XB  = RP + (size_t)800 * KP; // dead before first RP write

    {
        int total = NW * KP + 800 * KP + 4096 * KP;
        pack_k<<<(total + 255) / 256, 256, 0, stream>>>(u_lh, u_rh, w_score, u_lc, u_rc,
                                                        w_leaf_h, w_leaf_c, x, WT, WLT, XB);
    }
    // Leaf pre-activations via MFMA: XB(4096x416) @ WLT^T(800x416) -> PRE fp32
    tgemm_k<<<dim3(10, 32), 256, 0, stream>>>(XB, nullptr, WLT, nullptr, nullptr, nullptr,
                                              PRE, 1, 32, 0);
    leaf_norm_k<<<BB * TT, 256, 0, stream>>>(PRE, b_leaf_h, b_leaf_c, Hchart, HB, CB, CS);
    // Leaf transforms into interleaved planes
    tgemm_k<<<dim3(25, 32), 256, 0, stream>>>(HB, CB, WT, LP, RP, G, nullptr, 0, 32, 0);

    int off = TT;
    for (int level = 1; level < TT; ++level) {
        int L = TT - level;
        level_k<<<BB * L, 256, 0, stream>>>(Hchart, HB, CB, CS, LP, RP, G, b_h, b_c, level);
        if (level < TT - 1) {
            tgemm_k<<<dim3(25, L), 256, 0, stream>>>(HB, CB, WT, LP, RP, G, nullptr, 0, L, off);
        }
        off += L;
    }
}